// Round 1
// baseline (197.446 us; speedup 1.0000x reference)
//
#include <hip/hip_runtime.h>
#include <hip/hip_bf16.h>

// FractalTransformer fused kernel set for MI355X (gfx950).
// B=2, S=512, D=256, all fp32 I/O. Dominant cost: logit projection over
// [B,Sk,Sq,D] = 68.7 GFLOP -> bf16 MFMA, fully fused with swishmax (online
// flash-style reduction over Sk) so the big tensor is never materialized.

typedef __attribute__((ext_vector_type(8))) short short8;
typedef __attribute__((ext_vector_type(4))) float f32x4;
typedef __attribute__((ext_vector_type(4))) unsigned short ushort4v;

#define DD 256
#define SS 512

__device__ __forceinline__ unsigned short f2bf(float f) {
  unsigned int b = __float_as_uint(f);
  b += 0x7FFFu + ((b >> 16) & 1u);   // RNE
  return (unsigned short)(b >> 16);
}
__device__ __forceinline__ float bf2f(unsigned short u) {
  return __uint_as_float(((unsigned int)u) << 16);
}
__device__ __forceinline__ short8 cvt8(f32x4 lo, f32x4 hi) {
  short8 r;
  r[0]=(short)f2bf(lo[0]); r[1]=(short)f2bf(lo[1]);
  r[2]=(short)f2bf(lo[2]); r[3]=(short)f2bf(lo[3]);
  r[4]=(short)f2bf(hi[0]); r[5]=(short)f2bf(hi[1]);
  r[6]=(short)f2bf(hi[2]); r[7]=(short)f2bf(hi[3]);
  return r;
}
__device__ __forceinline__ void gload16(const void* g, void* l) {
  __builtin_amdgcn_global_load_lds(
      (const __attribute__((address_space(1))) void*)g,
      (__attribute__((address_space(3))) void*)l,
      16, 0, 0);
}

// ------------------------------------------------------------------
// out[M=1024,256] = A @ W^T (+res1)(+res2), bf16 MFMA, W read f32 + cvt.
// grid 64: (row-block 16) x (col-block 4); 4 waves, wave = 16 rows x 64 cols.
// ------------------------------------------------------------------
__global__ __launch_bounds__(256) void linear_one(
    const float* __restrict__ A, const float* __restrict__ W,
    const float* __restrict__ res1, const float* __restrict__ res2,
    float* __restrict__ out)
{
  const int bi = blockIdx.x;
  const int rb = (bi >> 2) * 64;
  const int cb = (bi & 3) * 64;
  const int tid = threadIdx.x;
  const int wv = tid >> 6, lane = tid & 63;
  const int g = lane >> 4, c = lane & 15;
  const int arow = rb + wv * 16 + c;

  f32x4 acc[4];
#pragma unroll
  for (int n = 0; n < 4; ++n) acc[n] = (f32x4){0.f, 0.f, 0.f, 0.f};

#pragma unroll
  for (int ks = 0; ks < 8; ++ks) {
    const int d0 = ks * 32 + g * 8;
    f32x4 a0 = *(const f32x4*)(A + arow * DD + d0);
    f32x4 a1 = *(const f32x4*)(A + arow * DD + d0 + 4);
    short8 av = cvt8(a0, a1);
#pragma unroll
    for (int n = 0; n < 4; ++n) {
      const int wrow = cb + n * 16 + c;
      f32x4 b0 = *(const f32x4*)(W + wrow * DD + d0);
      f32x4 b1 = *(const f32x4*)(W + wrow * DD + d0 + 4);
      short8 bv = cvt8(b0, b1);
      acc[n] = __builtin_amdgcn_mfma_f32_16x16x32_bf16(av, bv, acc[n], 0, 0, 0);
    }
  }
#pragma unroll
  for (int n = 0; n < 4; ++n) {
#pragma unroll
    for (int j = 0; j < 4; ++j) {
      const int ro = rb + wv * 16 + g * 4 + j;
      const int co = cb + n * 16 + c;
      float v = acc[n][j];
      if (res1) v += res1[ro * DD + co];
      if (res2) v += res2[ro * DD + co];
      out[ro * DD + co] = v;
    }
  }
}

// ------------------------------------------------------------------
// q = X + X@Wq^T (f32), k_bf = bf16(X + X@Wk^T), v_bf = bf16(X + X@Wv^T)
// ------------------------------------------------------------------
__global__ __launch_bounds__(256) void linear_qkv(
    const float* __restrict__ X,
    const float* __restrict__ Wq, const float* __restrict__ Wk,
    const float* __restrict__ Wv,
    float* __restrict__ qout, unsigned short* __restrict__ kout,
    unsigned short* __restrict__ vout)
{
  const int bi = blockIdx.x;
  const int rb = (bi >> 2) * 64;
  const int cb = (bi & 3) * 64;
  const int tid = threadIdx.x;
  const int wv = tid >> 6, lane = tid & 63;
  const int g = lane >> 4, c = lane & 15;
  const int arow = rb + wv * 16 + c;

  f32x4 aq[4], ak[4], avv[4];
#pragma unroll
  for (int n = 0; n < 4; ++n) {
    aq[n] = (f32x4){0.f, 0.f, 0.f, 0.f};
    ak[n] = (f32x4){0.f, 0.f, 0.f, 0.f};
    avv[n] = (f32x4){0.f, 0.f, 0.f, 0.f};
  }

#pragma unroll
  for (int ks = 0; ks < 8; ++ks) {
    const int d0 = ks * 32 + g * 8;
    f32x4 a0 = *(const f32x4*)(X + arow * DD + d0);
    f32x4 a1 = *(const f32x4*)(X + arow * DD + d0 + 4);
    short8 af = cvt8(a0, a1);
#pragma unroll
    for (int n = 0; n < 4; ++n) {
      const int wrow = cb + n * 16 + c;
      f32x4 q0 = *(const f32x4*)(Wq + wrow * DD + d0);
      f32x4 q1 = *(const f32x4*)(Wq + wrow * DD + d0 + 4);
      short8 bq = cvt8(q0, q1);
      aq[n] = __builtin_amdgcn_mfma_f32_16x16x32_bf16(af, bq, aq[n], 0, 0, 0);
      f32x4 k0 = *(const f32x4*)(Wk + wrow * DD + d0);
      f32x4 k1 = *(const f32x4*)(Wk + wrow * DD + d0 + 4);
      short8 bk = cvt8(k0, k1);
      ak[n] = __builtin_amdgcn_mfma_f32_16x16x32_bf16(af, bk, ak[n], 0, 0, 0);
      f32x4 v0 = *(const f32x4*)(Wv + wrow * DD + d0);
      f32x4 v1 = *(const f32x4*)(Wv + wrow * DD + d0 + 4);
      short8 bv = cvt8(v0, v1);
      avv[n] = __builtin_amdgcn_mfma_f32_16x16x32_bf16(af, bv, avv[n], 0, 0, 0);
    }
  }
#pragma unroll
  for (int n = 0; n < 4; ++n) {
#pragma unroll
    for (int j = 0; j < 4; ++j) {
      const int ro = rb + wv * 16 + g * 4 + j;
      const int co = cb + n * 16 + c;
      const float base = X[ro * DD + co];
      qout[ro * DD + co] = base + aq[n][j];
      kout[ro * DD + co] = f2bf(base + ak[n][j]);
      vout[ro * DD + co] = f2bf(base + avv[n][j]);
    }
  }
}

// ------------------------------------------------------------------
// Fused fractal attention. One WG per (b, sq); 8 waves x 64 lanes.
// L^T[e,sk] = sum_d A'[e,d] * k[sk,d],  A'[e,d] = (wal[e,d]+I)*q[sq,d].
// Online swishmax over sk (per-lane state, merged by shfl butterfly).
// LDS: double-buffered (k 32KB + v 32KB) bf16 tiles, 16B-granule XOR swizzle
// (gcol ^ (row&7)), staged via global_load_lds with pre-swizzled source.
// ------------------------------------------------------------------
__global__ __launch_bounds__(512, 2) void fractal_attn(
    const float* __restrict__ wal, const float* __restrict__ q,
    const unsigned short* __restrict__ kbf,
    const unsigned short* __restrict__ vbf,
    float* __restrict__ vsum)
{
  __shared__ char smem[2][65536];   // [buf][ k:32KB | v:32KB ]

  const int wg = blockIdx.x;        // 1024
  const int b = wg >> 9, sq = wg & 511;
  const int tid = threadIdx.x;
  const int wv = tid >> 6, lane = tid & 63;
  const int g = lane >> 4, c = lane & 15;

  auto stage = [&](int t) {
    const int buf = t & 1;
    const unsigned short* ksrc = kbf + (size_t)(b * SS + t * 64) * DD;
    const unsigned short* vsrc = vbf + (size_t)(b * SS + t * 64) * DD;
#pragma unroll
    for (int it = 0; it < 4; ++it) {
      const int p = wv * 256 + it * 64 + lane;   // 16B-granule index 0..2047
      const int row = p >> 5;
      const int gc = p & 31;
      const int sg = gc ^ (row & 7);             // inverse-swizzled source granule
      gload16(ksrc + row * DD + sg * 8,
              &smem[buf][(wv * 256 + it * 64) * 16]);
      gload16(vsrc + row * DD + sg * 8,
              &smem[buf][32768 + (wv * 256 + it * 64) * 16]);
    }
  };

  stage(0);   // in flight while we build A'

  // ---- A' fragments in registers: e in [32*wv, 32*wv+32) ----
  short8 afrag[2][8];
  {
    const float* qrow = q + (size_t)(b * SS + sq) * DD;
#pragma unroll
    for (int i = 0; i < 2; ++i) {
      const int e = wv * 32 + i * 16 + c;
      const float* wrow = wal + (size_t)e * DD;
#pragma unroll
      for (int ks = 0; ks < 8; ++ks) {
        const int d0 = ks * 32 + g * 8;
        f32x4 w0 = *(const f32x4*)(wrow + d0);
        f32x4 w1 = *(const f32x4*)(wrow + d0 + 4);
        // fold residual: += I
        w0[0] += (e == d0 + 0) ? 1.0f : 0.0f;
        w0[1] += (e == d0 + 1) ? 1.0f : 0.0f;
        w0[2] += (e == d0 + 2) ? 1.0f : 0.0f;
        w0[3] += (e == d0 + 3) ? 1.0f : 0.0f;
        w1[0] += (e == d0 + 4) ? 1.0f : 0.0f;
        w1[1] += (e == d0 + 5) ? 1.0f : 0.0f;
        w1[2] += (e == d0 + 6) ? 1.0f : 0.0f;
        w1[3] += (e == d0 + 7) ? 1.0f : 0.0f;
        f32x4 q0 = *(const f32x4*)(qrow + d0);
        f32x4 q1 = *(const f32x4*)(qrow + d0 + 4);
        afrag[i][ks] = cvt8(w0 * q0, w1 * q1);
      }
    }
  }

  // ---- online swishmax state (per lane: 8 e-values, partial over its sk) ----
  float mst[8], sst[8], vst[8];
#pragma unroll
  for (int s = 0; s < 8; ++s) { mst[s] = -1e30f; sst[s] = 0.f; vst[s] = 0.f; }

  for (int t = 0; t < 8; ++t) {
    __syncthreads();                 // drains vmcnt(0): buf[t&1] fully staged
    if (t < 7) stage(t + 1);         // prefetch next tile (overlaps compute)
    const char* kb = &smem[t & 1][0];
    const char* vb = kb + 32768;

    f32x4 acc[2][4];
#pragma unroll
    for (int i = 0; i < 2; ++i)
#pragma unroll
      for (int n = 0; n < 4; ++n) acc[i][n] = (f32x4){0.f, 0.f, 0.f, 0.f};

#pragma unroll
    for (int ks = 0; ks < 8; ++ks) {
      short8 bfr[4];
#pragma unroll
      for (int n = 0; n < 4; ++n) {
        const int row = n * 16 + c;                // row&7 == c&7
        const int gi = (g + ks * 4) ^ (c & 7);     // swizzled granule
        bfr[n] = *(const short8*)(kb + row * 512 + gi * 16);
      }
#pragma unroll
      for (int i = 0; i < 2; ++i)
#pragma unroll
        for (int n = 0; n < 4; ++n)
          acc[i][n] = __builtin_amdgcn_mfma_f32_16x16x32_bf16(
              afrag[i][ks], bfr[n], acc[i][n], 0, 0, 0);
    }

    // ---- online update; lane holds e = 32*wv + 16*i + 4*g + j, sk = 64t+16n+c
#pragma unroll
    for (int i = 0; i < 2; ++i) {
      ushort4v vq[4];
#pragma unroll
      for (int n = 0; n < 4; ++n) {
        const int row = n * 16 + c;
        const int g16 = (wv * 4 + i * 2 + (g >> 1)) ^ (c & 7);
        vq[n] = *(const ushort4v*)(vb + row * 512 + g16 * 16 + (g & 1) * 8);
      }
#pragma unroll
      for (int j = 0; j < 4; ++j) {
        const int s = i * 4 + j;
        const float L0 = acc[i][0][j], L1 = acc[i][1][j];
        const float L2 = acc[i][2][j], L3 = acc[i][3][j];
        const float tm = fmaxf(fmaxf(L0, L1), fmaxf(L2, L3));
        const float mn = fmaxf(mst[s], tm);
        const float corr = __expf(mst[s] - mn);
        mst[s] = mn;
        const float p0 = L0 * __expf(L0 - mn);
        const float p1 = L1 * __expf(L1 - mn);
        const float p2 = L2 * __expf(L2 - mn);
        const float p3 = L3 * __expf(L3 - mn);
        sst[s] = sst[s] * corr + fabsf(p0) + fabsf(p1) + fabsf(p2) + fabsf(p3);
        vst[s] = vst[s] * corr + bf2f(vq[0][j]) * p0 + bf2f(vq[1][j]) * p1 +
                 bf2f(vq[2][j]) * p2 + bf2f(vq[3][j]) * p3;
      }
    }
  }

  // ---- merge partial states across the 16 sk-lanes (same g => same e) ----
#pragma unroll
  for (int mask = 1; mask <= 8; mask <<= 1) {
#pragma unroll
    for (int s = 0; s < 8; ++s) {
      const float m2 = __shfl_xor(mst[s], mask);
      const float s2 = __shfl_xor(sst[s], mask);
      const float v2 = __shfl_xor(vst[s], mask);
      const float mn = fmaxf(mst[s], m2);
      const float c1 = __expf(mst[s] - mn);
      const float c2 = __expf(m2 - mn);
      sst[s] = sst[s] * c1 + s2 * c2;
      vst[s] = vst[s] * c1 + v2 * c2;
      mst[s] = mn;
    }
  }

  if (c == 0) {
    float* orow = vsum + (size_t)(b * SS + sq) * DD;
#pragma unroll
    for (int i = 0; i < 2; ++i)
#pragma unroll
      for (int j = 0; j < 4; ++j)
        orow[wv * 32 + i * 16 + g * 4 + j] =
            vst[i * 4 + j] / (sst[i * 4 + j] + 1.0f);
  }
}

// ------------------------------------------------------------------
extern "C" void kernel_launch(void* const* d_in, const int* in_sizes, int n_in,
                              void* d_out, int out_size, void* d_ws, size_t ws_size,
                              hipStream_t stream) {
  const float* x     = (const float*)d_in[0];
  const float* w_pre = (const float*)d_in[1];
  const float* w_q   = (const float*)d_in[2];
  const float* w_k   = (const float*)d_in[3];
  const float* w_va  = (const float*)d_in[4];
  const float* w_al  = (const float*)d_in[5];
  const float* w_vo  = (const float*)d_in[6];
  const float* w_end = (const float*)d_in[7];
  float* out = (float*)d_out;

  char* ws = (char*)d_ws;
  float* X    = (float*)(ws);
  float* q    = (float*)(ws + (1 << 20));
  float* vsum = (float*)(ws + (2 << 20));
  float* Y    = (float*)(ws + (3 << 20));
  unsigned short* k_bf = (unsigned short*)(ws + (4 << 20));
  unsigned short* v_bf = (unsigned short*)(ws + (4 << 20) + (512 << 10));

  // X = x @ w_pre^T
  linear_one<<<64, 256, 0, stream>>>(x, w_pre, nullptr, nullptr, X);
  // q/k/v = X + X @ W^T  (k,v to bf16)
  linear_qkv<<<64, 256, 0, stream>>>(X, w_q, w_k, w_va, q, k_bf, v_bf);
  // fused logits + swishmax + v-sum over Sk
  fractal_attn<<<1024, 512, 0, stream>>>(w_al, q, k_bf, v_bf, vsum);
  // Y = X + vsum + vsum @ w_vo^T
  linear_one<<<64, 256, 0, stream>>>(vsum, w_vo, vsum, X, Y);
  // out = Y @ w_end^T
  linear_one<<<64, 256, 0, stream>>>(Y, w_end, nullptr, nullptr, out);
}

// Round 2
// 132.209 us; speedup vs baseline: 1.4934x; 1.4934x over previous
//
#include <hip/hip_runtime.h>
#include <hip/hip_bf16.h>

// FractalTransformer fused kernels, round 2.
// Changes vs r1: (1) no-max-subtract swishmax accumulation (exp2-direct,
// log2e folded into q; single final e^{-m} correction) -> ~45% fewer VALU
// inst and no serial max chain; (2) KVBLK=32 + e-half split -> 64KB LDS,
// VGPR<=128, 2 WG/CU (occupancy 2x); (3) all weights pre-converted to bf16
// once (w_al gets +I folded) -> linears lose the W-cvt VALU and halve W
// bytes; grid 256. (4) hoisted LDS addressing (1 XOR per k-read).

typedef __attribute__((ext_vector_type(8))) short short8;
typedef __attribute__((ext_vector_type(4))) float f32x4;
typedef __attribute__((ext_vector_type(4))) unsigned short ushort4v;

#define DD 256
#define SS 512
#define LOG2E 1.4426950408889634f
#define LN2   0.6931471805599453f

__device__ __forceinline__ unsigned short f2bf(float f) {
  unsigned int b = __float_as_uint(f);
  b += 0x7FFFu + ((b >> 16) & 1u);   // RNE
  return (unsigned short)(b >> 16);
}
__device__ __forceinline__ float bf2f(unsigned short u) {
  return __uint_as_float(((unsigned int)u) << 16);
}
__device__ __forceinline__ short8 cvt8(f32x4 lo, f32x4 hi) {
  short8 r;
  r[0]=(short)f2bf(lo[0]); r[1]=(short)f2bf(lo[1]);
  r[2]=(short)f2bf(lo[2]); r[3]=(short)f2bf(lo[3]);
  r[4]=(short)f2bf(hi[0]); r[5]=(short)f2bf(hi[1]);
  r[6]=(short)f2bf(hi[2]); r[7]=(short)f2bf(hi[3]);
  return r;
}
__device__ __forceinline__ void gload16(const void* g, void* l) {
  __builtin_amdgcn_global_load_lds(
      (const __attribute__((address_space(1))) void*)g,
      (__attribute__((address_space(3))) void*)l,
      16, 0, 0);
}

// ------------------------------------------------------------------
// One-time: bf16-convert 6 weights + (w_al + I). out = 7 x [256][256] bf16.
// ------------------------------------------------------------------
__global__ __launch_bounds__(256) void prep_weights(
    const float* __restrict__ w0, const float* __restrict__ w1,
    const float* __restrict__ w2, const float* __restrict__ w3,
    const float* __restrict__ w4, const float* __restrict__ w5,
    const float* __restrict__ wal, unsigned short* __restrict__ out)
{
  const int bi = blockIdx.x;               // 7*32
  const int m = bi >> 5;
  const int off = ((bi & 31) * 256 + threadIdx.x) * 8;
  const float* src = m==0?w0: m==1?w1: m==2?w2: m==3?w3: m==4?w4: m==5?w5: wal;
  f32x4 a = *(const f32x4*)(src + off);
  f32x4 b = *(const f32x4*)(src + off + 4);
  if (m == 6) {                            // fold residual: + I
    const int e = off >> 8, d = off & 255;
#pragma unroll
    for (int jj = 0; jj < 4; ++jj) {
      if (e == d + jj)     a[jj] += 1.0f;
      if (e == d + 4 + jj) b[jj] += 1.0f;
    }
  }
  *(short8*)(out + (size_t)m * 65536 + off) = cvt8(a, b);
}

// ------------------------------------------------------------------
// out[1024,256] = A @ Wbf^T (+res1)(+res2). grid 256 = 64 rowblk x 4 colblk.
// 4 waves; wave = 16 rows x 16 cols (n=1), W read bf16 direct.
// ------------------------------------------------------------------
__global__ __launch_bounds__(256) void linear_bf(
    const float* __restrict__ A, const unsigned short* __restrict__ Wbf,
    const float* __restrict__ res1, const float* __restrict__ res2,
    float* __restrict__ out)
{
  const int bi = blockIdx.x;
  const int rb = (bi >> 2) * 16;
  const int cb = (bi & 3) * 64;
  const int tid = threadIdx.x;
  const int wv = tid >> 6, lane = tid & 63;
  const int g = lane >> 4, c = lane & 15;
  const int arow = rb + c;
  const int wrow = cb + wv * 16 + c;

  f32x4 acc = (f32x4){0.f, 0.f, 0.f, 0.f};
#pragma unroll
  for (int ks = 0; ks < 8; ++ks) {
    const int d0 = ks * 32 + g * 8;
    f32x4 a0 = *(const f32x4*)(A + arow * DD + d0);
    f32x4 a1 = *(const f32x4*)(A + arow * DD + d0 + 4);
    short8 av = cvt8(a0, a1);
    short8 bv = *(const short8*)(Wbf + wrow * DD + d0);
    acc = __builtin_amdgcn_mfma_f32_16x16x32_bf16(av, bv, acc, 0, 0, 0);
  }
#pragma unroll
  for (int j = 0; j < 4; ++j) {
    const int ro = rb + g * 4 + j;
    const int co = cb + wv * 16 + c;
    float v = acc[j];
    if (res1) v += res1[ro * DD + co];
    if (res2) v += res2[ro * DD + co];
    out[ro * DD + co] = v;
  }
}

// ------------------------------------------------------------------
// q = (X + X@Wq^T)*log2e (f32);  k,v = bf16(X + X@{Wk,Wv}^T)
// ------------------------------------------------------------------
__global__ __launch_bounds__(256) void linear_qkv(
    const float* __restrict__ X,
    const unsigned short* __restrict__ Wq, const unsigned short* __restrict__ Wk,
    const unsigned short* __restrict__ Wv,
    float* __restrict__ qout, unsigned short* __restrict__ kout,
    unsigned short* __restrict__ vout)
{
  const int bi = blockIdx.x;
  const int rb = (bi >> 2) * 16;
  const int cb = (bi & 3) * 64;
  const int tid = threadIdx.x;
  const int wv = tid >> 6, lane = tid & 63;
  const int g = lane >> 4, c = lane & 15;
  const int arow = rb + c;
  const int wrow = cb + wv * 16 + c;

  f32x4 aq = (f32x4){0.f,0.f,0.f,0.f};
  f32x4 ak = (f32x4){0.f,0.f,0.f,0.f};
  f32x4 av_ = (f32x4){0.f,0.f,0.f,0.f};
#pragma unroll
  for (int ks = 0; ks < 8; ++ks) {
    const int d0 = ks * 32 + g * 8;
    f32x4 a0 = *(const f32x4*)(X + arow * DD + d0);
    f32x4 a1 = *(const f32x4*)(X + arow * DD + d0 + 4);
    short8 af = cvt8(a0, a1);
    short8 bq = *(const short8*)(Wq + wrow * DD + d0);
    aq = __builtin_amdgcn_mfma_f32_16x16x32_bf16(af, bq, aq, 0, 0, 0);
    short8 bk = *(const short8*)(Wk + wrow * DD + d0);
    ak = __builtin_amdgcn_mfma_f32_16x16x32_bf16(af, bk, ak, 0, 0, 0);
    short8 bv = *(const short8*)(Wv + wrow * DD + d0);
    av_ = __builtin_amdgcn_mfma_f32_16x16x32_bf16(af, bv, av_, 0, 0, 0);
  }
#pragma unroll
  for (int j = 0; j < 4; ++j) {
    const int ro = rb + g * 4 + j;
    const int co = cb + wv * 16 + c;
    const float base = X[ro * DD + co];
    qout[ro * DD + co] = (base + aq[j]) * LOG2E;
    kout[ro * DD + co] = f2bf(base + ak[j]);
    vout[ro * DD + co] = f2bf(base + av_[j]);
  }
}

// ------------------------------------------------------------------
// Fused fractal attention v2. Grid 2048 = b(2) x sq(512) x e-half(2).
// 8 waves x 64 lanes; wave owns 16 e-rows. KVBLK=32, double-buffered
// k(16KB)+v(16KB) per buf = 64KB LDS -> 2 WG/CU.
// L2[e,sk] = sum_d A'[e,d]*k[sk,d], A' = (wal+I)*q*log2e (bf16).
// No-max accumulation: S += |L2*2^L2|, V += v*L2*2^L2, m = max(L2);
// final out = V*t/(S*t+1), t = ln2*2^-m.
// ------------------------------------------------------------------
__global__ __launch_bounds__(512, 4) void fractal_attn(
    const unsigned short* __restrict__ walI,   // bf16 (wal+I), [256][256]
    const float* __restrict__ q,               // f32, pre-scaled by log2e
    const unsigned short* __restrict__ kbf,
    const unsigned short* __restrict__ vbf,
    float* __restrict__ vsum)
{
  __shared__ char smem[2][32768];   // [buf][ k:16KB | v:16KB ]

  const int wg = blockIdx.x;        // 2048
  const int eh = wg & 1;
  const int sq = (wg >> 1) & 511;
  const int b  = wg >> 10;
  const int tid = threadIdx.x;
  const int wv = tid >> 6, lane = tid & 63;
  const int g = lane >> 4, c = lane & 15;

  // ---- staging: tile = 32 rows x 32 granules(16B); 2 granules/thread ----
  const unsigned short* kbase = kbf + (size_t)b * SS * DD;
  const unsigned short* vbase = vbf + (size_t)b * SS * DD;
  int srco[2];
#pragma unroll
  for (int it = 0; it < 2; ++it) {
    const int p = it * 512 + tid;            // granule 0..1023
    const int row = p >> 5, gc = p & 31;
    srco[it] = row * DD + (gc ^ (row & 7)) * 8;   // inverse-swizzled source
  }
  auto stage = [&](int t) {
    char* dst = (char*)smem[t & 1];
    const unsigned short* ks = kbase + t * 32 * DD;
    const unsigned short* vs = vbase + t * 32 * DD;
#pragma unroll
    for (int it = 0; it < 2; ++it) {
      gload16(ks + srco[it], dst + (it * 512 + tid) * 16);
      gload16(vs + srco[it], dst + 16384 + (it * 512 + tid) * 16);
    }
  };

  stage(0);   // in flight while we build A'

  // ---- A' fragments: wave owns e in [eh*128 + wv*16, +16) ----
  short8 afrag[8];
  {
    const float* qrow = q + (size_t)(b * SS + sq) * DD;
    const int e = eh * 128 + wv * 16 + c;
    const unsigned short* wrow = walI + (size_t)e * DD;
#pragma unroll
    for (int ks = 0; ks < 8; ++ks) {
      const int d0 = ks * 32 + g * 8;
      short8 w8 = *(const short8*)(wrow + d0);
      f32x4 q0 = *(const f32x4*)(qrow + d0);
      f32x4 q1 = *(const f32x4*)(qrow + d0 + 4);
      f32x4 lo, hi;
      lo[0] = bf2f((unsigned short)w8[0]) * q0[0];
      lo[1] = bf2f((unsigned short)w8[1]) * q0[1];
      lo[2] = bf2f((unsigned short)w8[2]) * q0[2];
      lo[3] = bf2f((unsigned short)w8[3]) * q0[3];
      hi[0] = bf2f((unsigned short)w8[4]) * q1[0];
      hi[1] = bf2f((unsigned short)w8[5]) * q1[1];
      hi[2] = bf2f((unsigned short)w8[6]) * q1[2];
      hi[3] = bf2f((unsigned short)w8[7]) * q1[3];
      afrag[ks] = cvt8(lo, hi);
    }
  }

  // ---- hoisted LDS addressing ----
  // k-read: addr(n,ks) = koff[n] ^ (ks<<6)  (bit-disjoint swizzle identity)
  const int cb2 = (c >> 2) & 1;
  int koff[2], voff[2];
#pragma unroll
  for (int n = 0; n < 2; ++n) {
    koff[n] = n * 8192 + c * 512 + ((g ^ (c & 3)) << 4) + (cb2 << 6);
    const int row = n * 16 + c;
    const int g16 = eh * 16 + wv * 2 + (g >> 1);      // v granule (e/8)
    voff[n] = 16384 + row * 512 + ((g16 ^ (c & 7)) << 4) + ((g & 1) << 3);
  }

  // ---- state: per lane 4 e-slots (e = eh*128 + wv*16 + g*4 + j) ----
  float mst[4], sst[4], vst[4];
#pragma unroll
  for (int j = 0; j < 4; ++j) { mst[j] = -1e30f; sst[j] = 0.f; vst[j] = 0.f; }

  for (int t = 0; t < 16; ++t) {
    __syncthreads();                 // buf[t&1] fully staged (vmcnt drain)
    if (t < 15) stage(t + 1);        // prefetch overlaps compute
    const char* kb = (const char*)smem[t & 1];

    f32x4 acc0 = (f32x4){0.f,0.f,0.f,0.f};
    f32x4 acc1 = (f32x4){0.f,0.f,0.f,0.f};
#pragma unroll
    for (int ks = 0; ks < 8; ++ks) {
      short8 b0 = *(const short8*)(kb + (koff[0] ^ (ks << 6)));
      short8 b1 = *(const short8*)(kb + (koff[1] ^ (ks << 6)));
      acc0 = __builtin_amdgcn_mfma_f32_16x16x32_bf16(afrag[ks], b0, acc0, 0, 0, 0);
      acc1 = __builtin_amdgcn_mfma_f32_16x16x32_bf16(afrag[ks], b1, acc1, 0, 0, 0);
    }
    ushort4v vq0 = *(const ushort4v*)(kb + voff[0]);
    ushort4v vq1 = *(const ushort4v*)(kb + voff[1]);

#pragma unroll
    for (int j = 0; j < 4; ++j) {
      const float L0 = acc0[j], L1 = acc1[j];
      mst[j] = fmaxf(mst[j], fmaxf(L0, L1));
      const float e0 = __builtin_amdgcn_exp2f(L0);
      const float e1 = __builtin_amdgcn_exp2f(L1);
      const float p0 = L0 * e0, p1 = L1 * e1;
      sst[j] += fabsf(p0) + fabsf(p1);
      vst[j] = fmaf(bf2f((unsigned short)vq0[j]), p0, vst[j]);
      vst[j] = fmaf(bf2f((unsigned short)vq1[j]), p1, vst[j]);
    }
  }

  // ---- merge across the 16 sk-lanes: plain add/max (no rescale needed) ----
#pragma unroll
  for (int mask = 1; mask <= 8; mask <<= 1) {
#pragma unroll
    for (int j = 0; j < 4; ++j) {
      mst[j] = fmaxf(mst[j], __shfl_xor(mst[j], mask));
      sst[j] += __shfl_xor(sst[j], mask);
      vst[j] += __shfl_xor(vst[j], mask);
    }
  }

  if (c == 0) {
    float* orow = vsum + (size_t)(b * SS + sq) * DD;
    f32x4 o;
#pragma unroll
    for (int j = 0; j < 4; ++j) {
      const float tt = LN2 * __builtin_amdgcn_exp2f(-mst[j]);
      o[j] = vst[j] * tt / (sst[j] * tt + 1.0f);
    }
    *(f32x4*)(orow + eh * 128 + wv * 16 + g * 4) = o;
  }
}

// ------------------------------------------------------------------
extern "C" void kernel_launch(void* const* d_in, const int* in_sizes, int n_in,
                              void* d_out, int out_size, void* d_ws, size_t ws_size,
                              hipStream_t stream) {
  const float* x     = (const float*)d_in[0];
  const float* w_pre = (const float*)d_in[1];
  const float* w_q   = (const float*)d_in[2];
  const float* w_k   = (const float*)d_in[3];
  const float* w_va  = (const float*)d_in[4];
  const float* w_al  = (const float*)d_in[5];
  const float* w_vo  = (const float*)d_in[6];
  const float* w_end = (const float*)d_in[7];
  float* out = (float*)d_out;

  char* ws = (char*)d_ws;
  float* X    = (float*)(ws);
  float* q    = (float*)(ws + (1 << 20));
  float* vsum = (float*)(ws + (2 << 20));
  float* Y    = (float*)(ws + (3 << 20));
  unsigned short* k_bf = (unsigned short*)(ws + (4 << 20));
  unsigned short* v_bf = (unsigned short*)(ws + (4 << 20) + (512 << 10));
  unsigned short* wbf  = (unsigned short*)(ws + (5 << 20));
  // wbf order: pre, q, k, va, vo, end, walI(+I)

  prep_weights<<<224, 256, 0, stream>>>(w_pre, w_q, w_k, w_va, w_vo, w_end,
                                        w_al, wbf);
  linear_bf<<<256, 256, 0, stream>>>(x, wbf + 0 * 65536, nullptr, nullptr, X);
  linear_qkv<<<256, 256, 0, stream>>>(X, wbf + 1 * 65536, wbf + 2 * 65536,
                                      wbf + 3 * 65536, q, k_bf, v_bf);
  fractal_attn<<<2048, 512, 0, stream>>>(wbf + 6 * 65536, q, k_bf, v_bf, vsum);
  linear_bf<<<256, 256, 0, stream>>>(vsum, wbf + 4 * 65536, vsum, X, Y);
  linear_bf<<<256, 256, 0, stream>>>(Y, wbf + 5 * 65536, nullptr, nullptr, out);
}

// Round 3
// 127.546 us; speedup vs baseline: 1.5480x; 1.0366x over previous
//
#include <hip/hip_runtime.h>
#include <hip/hip_bf16.h>

// FractalTransformer fused kernels, round 3.
// vs r2: (1) M_wave=32 (afrag[2][8]) -> 2 MFMAs per k B-fragment read, halving
// LDS read traffic per MFMA (LDS pipe was ~85% saturated); (2) v moves out of
// LDS entirely -> read f32 from global/L2 at exactly the per-lane float4 the
// update needs (no staging, no unpack); (3) k ds_read addresses fold to
// 2 base regs + immediate offsets (zero per-read VALU); (4) 4-wave WGs,
// grid 2048, launch_bounds(256,3) -> 12 waves/CU, no spill.

typedef __attribute__((ext_vector_type(8))) short short8;
typedef __attribute__((ext_vector_type(4))) float f32x4;

#define DD 256
#define SS 512
#define KVB 32
#define LOG2E 1.4426950408889634f
#define LN2   0.6931471805599453f

__device__ __forceinline__ unsigned short f2bf(float f) {
  unsigned int b = __float_as_uint(f);
  b += 0x7FFFu + ((b >> 16) & 1u);   // RNE
  return (unsigned short)(b >> 16);
}
__device__ __forceinline__ float bf2f(unsigned short u) {
  return __uint_as_float(((unsigned int)u) << 16);
}
__device__ __forceinline__ short8 cvt8(f32x4 lo, f32x4 hi) {
  short8 r;
  r[0]=(short)f2bf(lo[0]); r[1]=(short)f2bf(lo[1]);
  r[2]=(short)f2bf(lo[2]); r[3]=(short)f2bf(lo[3]);
  r[4]=(short)f2bf(hi[0]); r[5]=(short)f2bf(hi[1]);
  r[6]=(short)f2bf(hi[2]); r[7]=(short)f2bf(hi[3]);
  return r;
}
__device__ __forceinline__ void gload16(const void* g, void* l) {
  __builtin_amdgcn_global_load_lds(
      (const __attribute__((address_space(1))) void*)g,
      (__attribute__((address_space(3))) void*)l,
      16, 0, 0);
}

// ------------------------------------------------------------------
// One-time: bf16-convert 6 weights + (w_al + I). out = 7 x [256][256] bf16.
// ------------------------------------------------------------------
__global__ __launch_bounds__(256) void prep_weights(
    const float* __restrict__ w0, const float* __restrict__ w1,
    const float* __restrict__ w2, const float* __restrict__ w3,
    const float* __restrict__ w4, const float* __restrict__ w5,
    const float* __restrict__ wal, unsigned short* __restrict__ out)
{
  const int bi = blockIdx.x;               // 7*32
  const int m = bi >> 5;
  const int off = ((bi & 31) * 256 + threadIdx.x) * 8;
  const float* src = m==0?w0: m==1?w1: m==2?w2: m==3?w3: m==4?w4: m==5?w5: wal;
  f32x4 a = *(const f32x4*)(src + off);
  f32x4 b = *(const f32x4*)(src + off + 4);
  if (m == 6) {                            // fold residual: + I
    const int e = off >> 8, d = off & 255;
#pragma unroll
    for (int jj = 0; jj < 4; ++jj) {
      if (e == d + jj)     a[jj] += 1.0f;
      if (e == d + 4 + jj) b[jj] += 1.0f;
    }
  }
  *(short8*)(out + (size_t)m * 65536 + off) = cvt8(a, b);
}

// ------------------------------------------------------------------
// out[1024,256] = A @ Wbf^T (+res1)(+res2). grid 256 = 64 rowblk x 4 colblk.
// ------------------------------------------------------------------
__global__ __launch_bounds__(256) void linear_bf(
    const float* __restrict__ A, const unsigned short* __restrict__ Wbf,
    const float* __restrict__ res1, const float* __restrict__ res2,
    float* __restrict__ out)
{
  const int bi = blockIdx.x;
  const int rb = (bi >> 2) * 16;
  const int cb = (bi & 3) * 64;
  const int tid = threadIdx.x;
  const int wv = tid >> 6, lane = tid & 63;
  const int g = lane >> 4, c = lane & 15;
  const int arow = rb + c;
  const int wrow = cb + wv * 16 + c;

  f32x4 acc = (f32x4){0.f, 0.f, 0.f, 0.f};
#pragma unroll
  for (int ks = 0; ks < 8; ++ks) {
    const int d0 = ks * 32 + g * 8;
    f32x4 a0 = *(const f32x4*)(A + arow * DD + d0);
    f32x4 a1 = *(const f32x4*)(A + arow * DD + d0 + 4);
    short8 av = cvt8(a0, a1);
    short8 bv = *(const short8*)(Wbf + wrow * DD + d0);
    acc = __builtin_amdgcn_mfma_f32_16x16x32_bf16(av, bv, acc, 0, 0, 0);
  }
#pragma unroll
  for (int j = 0; j < 4; ++j) {
    const int ro = rb + g * 4 + j;
    const int co = cb + wv * 16 + c;
    float v = acc[j];
    if (res1) v += res1[ro * DD + co];
    if (res2) v += res2[ro * DD + co];
    out[ro * DD + co] = v;
  }
}

// ------------------------------------------------------------------
// q = (X + X@Wq^T)*log2e (f32);  k = bf16(X + X@Wk^T);  v = f32(X + X@Wv^T)
// ------------------------------------------------------------------
__global__ __launch_bounds__(256) void linear_qkv(
    const float* __restrict__ X,
    const unsigned short* __restrict__ Wq, const unsigned short* __restrict__ Wk,
    const unsigned short* __restrict__ Wv,
    float* __restrict__ qout, unsigned short* __restrict__ kout,
    float* __restrict__ vout)
{
  const int bi = blockIdx.x;
  const int rb = (bi >> 2) * 16;
  const int cb = (bi & 3) * 64;
  const int tid = threadIdx.x;
  const int wv = tid >> 6, lane = tid & 63;
  const int g = lane >> 4, c = lane & 15;
  const int arow = rb + c;
  const int wrow = cb + wv * 16 + c;

  f32x4 aq = (f32x4){0.f,0.f,0.f,0.f};
  f32x4 ak = (f32x4){0.f,0.f,0.f,0.f};
  f32x4 av_ = (f32x4){0.f,0.f,0.f,0.f};
#pragma unroll
  for (int ks = 0; ks < 8; ++ks) {
    const int d0 = ks * 32 + g * 8;
    f32x4 a0 = *(const f32x4*)(X + arow * DD + d0);
    f32x4 a1 = *(const f32x4*)(X + arow * DD + d0 + 4);
    short8 af = cvt8(a0, a1);
    short8 bq = *(const short8*)(Wq + wrow * DD + d0);
    aq = __builtin_amdgcn_mfma_f32_16x16x32_bf16(af, bq, aq, 0, 0, 0);
    short8 bk = *(const short8*)(Wk + wrow * DD + d0);
    ak = __builtin_amdgcn_mfma_f32_16x16x32_bf16(af, bk, ak, 0, 0, 0);
    short8 bv = *(const short8*)(Wv + wrow * DD + d0);
    av_ = __builtin_amdgcn_mfma_f32_16x16x32_bf16(af, bv, av_, 0, 0, 0);
  }
#pragma unroll
  for (int j = 0; j < 4; ++j) {
    const int ro = rb + g * 4 + j;
    const int co = cb + wv * 16 + c;
    const float base = X[ro * DD + co];
    qout[ro * DD + co] = (base + aq[j]) * LOG2E;
    kout[ro * DD + co] = f2bf(base + ak[j]);
    vout[ro * DD + co] = base + av_[j];
  }
}

// ------------------------------------------------------------------
// Fused fractal attention v3. Grid 2048 = b x sq x e-half. 4 waves x 64.
// Wave owns 32 e-rows (i in {0,1}). KVB=32. LDS: k only, double-buffered
// 2 x 16KB. v read straight from global f32 (L2-resident).
// ------------------------------------------------------------------
__global__ __launch_bounds__(256, 3) void fractal_attn(
    const unsigned short* __restrict__ walI,   // bf16 (wal+I), [256][256]
    const float* __restrict__ q,               // f32, pre-scaled by log2e
    const unsigned short* __restrict__ kbf,    // bf16 [b][s][d]
    const float* __restrict__ vf,              // f32  [b][s][d]
    float* __restrict__ vsum)
{
  __shared__ char smem[2][16384];   // k tiles only

  const int wg = blockIdx.x;        // 2048
  const int eh = wg & 1;
  const int sq = (wg >> 1) & 511;
  const int b  = wg >> 10;
  const int tid = threadIdx.x;      // 256
  const int wv = tid >> 6, lane = tid & 63;
  const int g = lane >> 4, c = lane & 15;

  // ---- k staging: tile = 32 rows x 32 granules(16B); 4 granules/thread ----
  const unsigned short* kbase = kbf + (size_t)b * SS * DD;
  int srco[4];
#pragma unroll
  for (int it = 0; it < 4; ++it) {
    const int p = it * 256 + tid;            // granule 0..1023
    const int row = p >> 5, gc = p & 31;
    srco[it] = row * DD + (gc ^ (row & 7)) * 8;   // inverse-swizzled source
  }
  auto stage = [&](int t) {
    char* dst = (char*)smem[t & 1];
    const unsigned short* ks = kbase + t * KVB * DD;
#pragma unroll
    for (int it = 0; it < 4; ++it)
      gload16(ks + srco[it], dst + (it * 256 + tid) * 16);
  };

  stage(0);   // in flight while we build A'

  // ---- A' fragments: wave owns e in [eh*128 + wv*32, +32) ----
  short8 afrag[2][8];
  {
    const float* qrow = q + (size_t)(b * SS + sq) * DD;
#pragma unroll
    for (int i = 0; i < 2; ++i) {
      const int e = eh * 128 + wv * 32 + i * 16 + c;
      const unsigned short* wrow = walI + (size_t)e * DD;
#pragma unroll
      for (int ks = 0; ks < 8; ++ks) {
        const int d0 = ks * 32 + g * 8;
        short8 w8 = *(const short8*)(wrow + d0);
        f32x4 q0 = *(const f32x4*)(qrow + d0);
        f32x4 q1 = *(const f32x4*)(qrow + d0 + 4);
        f32x4 lo, hi;
        lo[0] = bf2f((unsigned short)w8[0]) * q0[0];
        lo[1] = bf2f((unsigned short)w8[1]) * q0[1];
        lo[2] = bf2f((unsigned short)w8[2]) * q0[2];
        lo[3] = bf2f((unsigned short)w8[3]) * q0[3];
        hi[0] = bf2f((unsigned short)w8[4]) * q1[0];
        hi[1] = bf2f((unsigned short)w8[5]) * q1[1];
        hi[2] = bf2f((unsigned short)w8[6]) * q1[2];
        hi[3] = bf2f((unsigned short)w8[7]) * q1[3];
        afrag[i][ks] = cvt8(lo, hi);
      }
    }
  }

  // ---- k-read bases: addr(n,ks) = base[ks&1] + n*8192 + (ks>>1)*128 ----
  // granule G = g + 4*ks, swizzled gi = G ^ (c&7); bit6 is the only XOR bit
  // shared with ks; bits 7-8 (ks>>1) are pure adds.
  const int kbA = c * 512 + ((g ^ (c & 3)) << 4) + (((c >> 2) & 1) << 6);
  const int kbB = kbA ^ 64;

  // ---- v global offsets (f32): row n*16+c, col = e-slot base ----
  const float* vwg = vf + (size_t)b * SS * DD;
  int voffe[2][2];
#pragma unroll
  for (int n = 0; n < 2; ++n)
#pragma unroll
    for (int i = 0; i < 2; ++i)
      voffe[n][i] = (n * 16 + c) * DD + eh * 128 + wv * 32 + i * 16 + g * 4;

  // ---- state: 8 e-slots per lane (e = eh*128+wv*32+i*16+g*4+j) ----
  float mst[8], sst[8], vst[8];
#pragma unroll
  for (int s = 0; s < 8; ++s) { mst[s] = -1e30f; sst[s] = 0.f; vst[s] = 0.f; }

  for (int t = 0; t < 16; ++t) {
    __syncthreads();                 // buf[t&1] fully staged (vmcnt drain)

    // v loads for THIS tile first (older in vmcnt), then prefetch next k.
    const float* vt = vwg + (size_t)t * KVB * DD;
    f32x4 vv[2][2];
#pragma unroll
    for (int n = 0; n < 2; ++n)
#pragma unroll
      for (int i = 0; i < 2; ++i)
        vv[n][i] = *(const f32x4*)(vt + voffe[n][i]);
    if (t < 15) stage(t + 1);

    const char* kb = (const char*)smem[t & 1];
    f32x4 acc[2][2];
#pragma unroll
    for (int i = 0; i < 2; ++i)
#pragma unroll
      for (int n = 0; n < 2; ++n) acc[i][n] = (f32x4){0.f,0.f,0.f,0.f};

#pragma unroll
    for (int ks2 = 0; ks2 < 4; ++ks2) {
      short8 bA0 = *(const short8*)(kb + kbA + ks2 * 128);
      short8 bA1 = *(const short8*)(kb + kbA + ks2 * 128 + 8192);
      acc[0][0] = __builtin_amdgcn_mfma_f32_16x16x32_bf16(afrag[0][2*ks2], bA0, acc[0][0], 0, 0, 0);
      acc[1][0] = __builtin_amdgcn_mfma_f32_16x16x32_bf16(afrag[1][2*ks2], bA0, acc[1][0], 0, 0, 0);
      acc[0][1] = __builtin_amdgcn_mfma_f32_16x16x32_bf16(afrag[0][2*ks2], bA1, acc[0][1], 0, 0, 0);
      acc[1][1] = __builtin_amdgcn_mfma_f32_16x16x32_bf16(afrag[1][2*ks2], bA1, acc[1][1], 0, 0, 0);
      short8 bB0 = *(const short8*)(kb + kbB + ks2 * 128);
      short8 bB1 = *(const short8*)(kb + kbB + ks2 * 128 + 8192);
      acc[0][0] = __builtin_amdgcn_mfma_f32_16x16x32_bf16(afrag[0][2*ks2+1], bB0, acc[0][0], 0, 0, 0);
      acc[1][0] = __builtin_amdgcn_mfma_f32_16x16x32_bf16(afrag[1][2*ks2+1], bB0, acc[1][0], 0, 0, 0);
      acc[0][1] = __builtin_amdgcn_mfma_f32_16x16x32_bf16(afrag[0][2*ks2+1], bB1, acc[0][1], 0, 0, 0);
      acc[1][1] = __builtin_amdgcn_mfma_f32_16x16x32_bf16(afrag[1][2*ks2+1], bB1, acc[1][1], 0, 0, 0);
    }

    // ---- online update: lane element (e-slot s=i*4+j, sk = t*32+n*16+c) ----
#pragma unroll
    for (int i = 0; i < 2; ++i) {
#pragma unroll
      for (int j = 0; j < 4; ++j) {
        const int s = i * 4 + j;
        const float L0 = acc[i][0][j], L1 = acc[i][1][j];
        mst[s] = fmaxf(fmaxf(mst[s], L0), L1);     // v_max3
        const float e0 = __builtin_amdgcn_exp2f(L0);
        const float e1 = __builtin_amdgcn_exp2f(L1);
        const float p0 = L0 * e0, p1 = L1 * e1;
        sst[s] += fabsf(p0) + fabsf(p1);
        vst[s] = fmaf(vv[0][i][j], p0, vst[s]);
        vst[s] = fmaf(vv[1][i][j], p1, vst[s]);
      }
    }
  }

  // ---- merge across the 16 sk-lanes (same g => same e) ----
#pragma unroll
  for (int mask = 1; mask <= 8; mask <<= 1) {
#pragma unroll
    for (int s = 0; s < 8; ++s) {
      mst[s] = fmaxf(mst[s], __shfl_xor(mst[s], mask));
      sst[s] += __shfl_xor(sst[s], mask);
      vst[s] += __shfl_xor(vst[s], mask);
    }
  }

  if (c == 0) {
    float* orow = vsum + (size_t)(b * SS + sq) * DD;
#pragma unroll
    for (int i = 0; i < 2; ++i) {
      f32x4 o;
#pragma unroll
      for (int j = 0; j < 4; ++j) {
        const int s = i * 4 + j;
        const float tt = LN2 * __builtin_amdgcn_exp2f(-mst[s]);
        o[j] = vst[s] * tt / (sst[s] * tt + 1.0f);
      }
      *(f32x4*)(orow + eh * 128 + wv * 32 + i * 16 + g * 4) = o;
    }
  }
}

// ------------------------------------------------------------------
extern "C" void kernel_launch(void* const* d_in, const int* in_sizes, int n_in,
                              void* d_out, int out_size, void* d_ws, size_t ws_size,
                              hipStream_t stream) {
  const float* x     = (const float*)d_in[0];
  const float* w_pre = (const float*)d_in[1];
  const float* w_q   = (const float*)d_in[2];
  const float* w_k   = (const float*)d_in[3];
  const float* w_va  = (const float*)d_in[4];
  const float* w_al  = (const float*)d_in[5];
  const float* w_vo  = (const float*)d_in[6];
  const float* w_end = (const float*)d_in[7];
  float* out = (float*)d_out;

  char* ws = (char*)d_ws;
  float* X    = (float*)(ws);
  float* q    = (float*)(ws + (1 << 20));
  float* vsum = (float*)(ws + (2 << 20));
  float* Y    = (float*)(ws + (3 << 20));
  unsigned short* k_bf = (unsigned short*)(ws + (4 << 20));          // 512KB
  float* v_f32         = (float*)(ws + (4 << 20) + (512 << 10));    // 1MB
  unsigned short* wbf  = (unsigned short*)(ws + (5 << 20) + (512 << 10));
  // wbf order: pre, q, k, va, vo, end, walI(+I)

  prep_weights<<<224, 256, 0, stream>>>(w_pre, w_q, w_k, w_va, w_vo, w_end,
                                        w_al, wbf);
  linear_bf<<<256, 256, 0, stream>>>(x, wbf + 0 * 65536, nullptr, nullptr, X);
  linear_qkv<<<256, 256, 0, stream>>>(X, wbf + 1 * 65536, wbf + 2 * 65536,
                                      wbf + 3 * 65536, q, k_bf, v_f32);
  fractal_attn<<<2048, 256, 0, stream>>>(wbf + 6 * 65536, q, k_bf, v_f32, vsum);
  linear_bf<<<256, 256, 0, stream>>>(vsum, wbf + 4 * 65536, vsum, X, Y);
  linear_bf<<<256, 256, 0, stream>>>(Y, wbf + 5 * 65536, nullptr, nullptr, out);
}